// Round 5
// baseline (166.952 us; speedup 1.0000x reference)
//
#include <hip/hip_runtime.h>

#define DIM 160
#define TW 32
#define TH 16
#define RROWS (TH + 6)        // 22
#define CHUNK 10
#define NCHUNK (DIM / CHUNK)  // 16
#define NBATCH 2
#define NTOT 8192000.0f       // 2 * 160^3
#define EPS_S 13841.287f      // 1e-6 * 343^4

__device__ __forceinline__ void row_stage(
    const float* __restrict__ Ip, const float* __restrict__ Jp,
    bool rowValid, bool ok0, bool ok1, bool ok2,
    float (* __restrict__ rsp)[RROWS][TW], int rr, int cc)
{
    float4 a0={0,0,0,0}, a1={0,0,0,0}, a2={0,0,0,0};
    float4 b0={0,0,0,0}, b1={0,0,0,0}, b2={0,0,0,0};
    if (rowValid) {
        if (ok0) { a0 = *(const float4*)(Ip);     b0 = *(const float4*)(Jp);     }
        if (ok1) { a1 = *(const float4*)(Ip + 4); b1 = *(const float4*)(Jp + 4); }
        if (ok2) { a2 = *(const float4*)(Ip + 8); b2 = *(const float4*)(Jp + 8); }
    }
    float vI[12] = {a0.x,a0.y,a0.z,a0.w, a1.x,a1.y,a1.z,a1.w, a2.x,a2.y,a2.z,a2.w};
    float vJ[12] = {b0.x,b0.y,b0.z,b0.w, b1.x,b1.y,b1.z,b1.w, b2.x,b2.y,b2.z,b2.w};

    float sI=0.f, sJ=0.f, sI2=0.f, sJ2=0.f, sIJ=0.f;
#pragma unroll
    for (int i = 1; i < 8; ++i) {
        float a = vI[i], c = vJ[i];
        sI += a; sJ += c;
        sI2 = fmaf(a, a, sI2);
        sJ2 = fmaf(c, c, sJ2);
        sIJ = fmaf(a, c, sIJ);
    }
    float wI[4], wJ[4], wI2[4], wJ2[4], wIJ[4];
    wI[0]=sI; wJ[0]=sJ; wI2[0]=sI2; wJ2[0]=sJ2; wIJ[0]=sIJ;
#pragma unroll
    for (int k = 1; k < 4; ++k) {
        float an = vI[7+k], cn = vJ[7+k];
        float ao = vI[k],   co = vJ[k];
        sI  += an - ao;
        sJ  += cn - co;
        sI2 += fmaf(an, an, -(ao*ao));
        sJ2 += fmaf(cn, cn, -(co*co));
        sIJ += fmaf(an, cn, -(ao*co));
        wI[k]=sI; wJ[k]=sJ; wI2[k]=sI2; wJ2[k]=sJ2; wIJ[k]=sIJ;
    }
    *(float4*)&rsp[0][rr][cc] = make_float4(wI[0],  wI[1],  wI[2],  wI[3]);
    *(float4*)&rsp[1][rr][cc] = make_float4(wJ[0],  wJ[1],  wJ[2],  wJ[3]);
    *(float4*)&rsp[2][rr][cc] = make_float4(wI2[0], wI2[1], wI2[2], wI2[3]);
    *(float4*)&rsp[3][rr][cc] = make_float4(wJ2[0], wJ2[1], wJ2[2], wJ2[3]);
    *(float4*)&rsp[4][rr][cc] = make_float4(wIJ[0], wIJ[1], wIJ[2], wIJ[3]);
}

__device__ __forceinline__ float lncc_term(float SI, float SJ, float SI2,
                                           float SJ2, float SIJ)
{
    // scale-free: work on raw 343-sums; eps scaled by 343^4
    float cross = fmaf(SIJ, 343.f, -(SI * SJ));
    float vI    = fmaf(SI2, 343.f, -(SI * SI));
    float vJ    = fmaf(SJ2, 343.f, -(SJ * SJ));
    float den   = fmaf(vI, vJ, EPS_S);
    return cross * cross * __builtin_amdgcn_rcpf(den);
}

__global__ __launch_bounds__(256) void lncc_fused_kernel(
    const float* __restrict__ I,
    const float* __restrict__ J,
    float* __restrict__ out)
{
    __shared__ __align__(16) float rs[2][5][RROWS][TW];
    __shared__ float wsum[4];

    const int tid = threadIdx.x;
    const int tx = tid & 15;          // col-stage: w-pair
    const int ty = tid >> 4;          // col-stage: h
    const int rr = tid >> 3;          // row-stage: row 0..31 (active < 22)
    const int rg = tid & 7;           // row-stage: 4-col group
    const int cc = 4 * rg;
    const bool rowActive = (rr < RROWS);

    const int tw0 = blockIdx.x * TW;
    const int th0 = blockIdx.y * TH;
    const int bz  = blockIdx.z;
    const int b     = bz >> 4;        // NCHUNK == 16
    const int chunk = bz & 15;
    const int z0  = chunk * CHUNK;

    const size_t plane = (size_t)DIM * DIM;
    const float* Ib = I + (size_t)b * DIM * plane;
    const float* Jb = J + (size_t)b * DIM * plane;

    const int gh = th0 + rr - 3;
    const bool rowValid = rowActive && ((unsigned)gh < (unsigned)DIM);
    const int gw0 = tw0 + cc - 4;
    const bool ok0 = (unsigned)gw0       <= (unsigned)(DIM - 4);
    const bool ok1 = (unsigned)(gw0 + 4) <= (unsigned)(DIM - 4);
    const bool ok2 = (unsigned)(gw0 + 8) <= (unsigned)(DIM - 4);
    const ptrdiff_t rowbase = (ptrdiff_t)gh * DIM + gw0;
    const float* IpBase = Ib + rowbase;   // + zin*plane per step (deref-guarded)
    const float* JpBase = Jb + rowbase;

    // z-ring: slot written = step % 7 (static via unroll); sum is rotation-invariant
    float rngx[5][7], rngy[5][7];
    float Sx[5], Sy[5];
#pragma unroll
    for (int f = 0; f < 5; ++f) {
        Sx[f] = 0.f; Sy[f] = 0.f;
#pragma unroll
        for (int k = 0; k < 7; ++k) { rngx[f][k] = 0.f; rngy[f][k] = 0.f; }
    }

    float acc = 0.f;
    int p = 0;
    int zin = z0 - 3;
    int s = 0;

#define STEP(SLOT) {                                                          \
    const bool zv = ((unsigned)zin < (unsigned)DIM);                          \
    float Cx[5] = {0.f,0.f,0.f,0.f,0.f};                                      \
    float Cy[5] = {0.f,0.f,0.f,0.f,0.f};                                      \
    if (zv) {                                                                 \
        if (rowActive) {                                                      \
            const float* Ip = IpBase + (ptrdiff_t)zin * (ptrdiff_t)plane;     \
            const float* Jp = JpBase + (ptrdiff_t)zin * (ptrdiff_t)plane;     \
            row_stage(Ip, Jp, rowValid, ok0, ok1, ok2, rs[p], rr, cc);        \
        }                                                                     \
        __syncthreads();                                                      \
        _Pragma("unroll")                                                     \
        for (int dr = 0; dr < 7; ++dr) {                                      \
            _Pragma("unroll")                                                 \
            for (int f = 0; f < 5; ++f) {                                     \
                const float2 v = *(const float2*)&rs[p][f][ty + dr][2 * tx];  \
                Cx[f] += v.x; Cy[f] += v.y;                                   \
            }                                                                 \
        }                                                                     \
        p ^= 1;                                                               \
    }                                                                         \
    _Pragma("unroll")                                                         \
    for (int f = 0; f < 5; ++f) {                                             \
        Sx[f] += Cx[f] - rngx[f][SLOT]; rngx[f][SLOT] = Cx[f];                \
        Sy[f] += Cy[f] - rngy[f][SLOT]; rngy[f][SLOT] = Cy[f];                \
    }                                                                         \
    if (s >= 6) {                                                             \
        acc += lncc_term(Sx[0], Sx[1], Sx[2], Sx[3], Sx[4]);                  \
        acc += lncc_term(Sy[0], Sy[1], Sy[2], Sy[3], Sy[4]);                  \
    }                                                                         \
    ++zin; ++s;                                                               \
}

    // 16 steps total (CHUNK+6): 2 groups of 7 (shared code) + 2 peeled (slots 0,1)
#pragma unroll 1
    for (int g = 0; g < 2; ++g) {
        STEP(0) STEP(1) STEP(2) STEP(3) STEP(4) STEP(5) STEP(6)
    }
    STEP(0) STEP(1)
#undef STEP

    // ---------- block reduce -> one atomic ----------
#pragma unroll
    for (int off = 32; off > 0; off >>= 1)
        acc += __shfl_down(acc, off, 64);
    if ((tid & 63) == 0) wsum[tid >> 6] = acc;
    __syncthreads();
    if (tid == 0) {
        float t = wsum[0] + wsum[1] + wsum[2] + wsum[3];
        atomicAdd(out, t * (-1.0f / NTOT));
    }
}

extern "C" void kernel_launch(void* const* d_in, const int* in_sizes, int n_in,
                              void* d_out, int out_size, void* d_ws, size_t ws_size,
                              hipStream_t stream) {
    const float* I = (const float*)d_in[0];
    const float* J = (const float*)d_in[1];
    float* out = (float*)d_out;

    hipMemsetAsync(out, 0, sizeof(float), stream);

    dim3 grid(DIM / TW, DIM / TH, NBATCH * NCHUNK);   // 5 x 10 x 32 = 1600 blocks
    dim3 block(256);
    lncc_fused_kernel<<<grid, block, 0, stream>>>(I, J, out);
}